// Round 6
// baseline (112.075 us; speedup 1.0000x reference)
//
#include <hip/hip_runtime.h>

#define MAXP 1048576           // static pair bound (MAX_PAIRS)
#define NATOMS 8192
#define D2_CUT 0x1.8ffffep+4f  // fl(sqrt(s))<5  <=>  s < 25-2^-19
#define CINV 0.175f            // 7/40: 7^3=343 cells, width 5.714 > 5.0004 (conservative)
#define CAP 192                // max hits/row (avg ~67)
#define CAPL 1024              // staged candidates cap (mean 645, max ~730 observed regime)

// d_ws layout (float offsets). Total 54784 floats = 214 KB (r5-proven safe).
#define W_SORTPOS 0            // float4[8192] cell-sorted (x,y,z,sq)
#define W_SORTID  32768        // u16[8192] sorted slot -> original atom id
#define W_ROWCNT  36864        // int[8192]
#define W_ROWOFF  45056        // int[8192]
#define W_CELLOFF 53248        // int[344], padded to 512
#define W_CELLCNT 53760        // int[344], padded to 512
#define W_CELLCUR 54272        // int[344], padded to 512

__device__ __forceinline__ float sq3_nc(float x, float y, float z) {
#pragma clang fp contract(off)
  float a = x * x;
  float b = y * y;
  float c = z * z;
  return (a + b) + c;
}

// mask per _pairwise_dist: sq_i + sq_j - 2*(x @ x.T); BLAS K=3 FMA chain (bit-exact, proven)
__device__ __forceinline__ float d2_gram(float xi, float yi, float zi, float sqi,
                                         float xj, float yj, float zj, float sqj) {
#pragma clang fp contract(off)
  float g = xi * xj;
  g = __builtin_fmaf(yi, yj, g);
  g = __builtin_fmaf(zi, zj, g);
  float t = sqi + sqj;
  float d2 = t - 2.0f * g;
  return d2;
}

__device__ __forceinline__ float d2_direct(float xi, float yi, float zi,
                                           float xj, float yj, float zj) {
#pragma clang fp contract(off)
  float dx = xj - xi;
  float dy = yj - yi;
  float dz = zj - zi;
  float a = dx * dx;
  float b = dy * dy;
  float c = dz * dz;
  return (a + b) + c;
}

__device__ __forceinline__ int cellco(float v) {
  int c = (int)(v * CINV);
  return c < 0 ? 0 : (c > 6 ? 6 : c);
}

// K0: zero 16.8 MB output (padding must be exactly 0) + zero cell counters.
__global__ __launch_bounds__(256) void nl_pack(float* __restrict__ out,
                                               float* __restrict__ ws) {
  const int gtid = blockIdx.x * 256 + threadIdx.x;  // 65536 threads
  float4* o4 = (float4*)out;                        // 4*MAXP floats = 1,048,576 float4
#pragma unroll
  for (int k = 0; k < 16; ++k)
    o4[k * 65536 + gtid] = make_float4(0.f, 0.f, 0.f, 0.f);
  if (gtid < 512) ((int*)(ws + W_CELLCNT))[gtid] = 0;
}

// K1: per-atom cell histogram.
__global__ __launch_bounds__(256) void nl_cellcount(const float* __restrict__ pos,
                                                    float* __restrict__ ws) {
  const int a = blockIdx.x * 256 + threadIdx.x;  // 8192 threads
  float x = pos[3 * a], y = pos[3 * a + 1], z = pos[3 * a + 2];
  int cl = cellco(x) + 7 * cellco(y) + 49 * cellco(z);
  atomicAdd(&((int*)(ws + W_CELLCNT))[cl], 1);
}

// K2: tiny 343-scan -> celloff[344]; zero cellcur.
__global__ __launch_bounds__(512) void nl_cellscan(float* __restrict__ ws) {
  const int* cellcnt = (const int*)(ws + W_CELLCNT);
  int* celloff = (int*)(ws + W_CELLOFF);
  int* cellcur = (int*)(ws + W_CELLCUR);
  __shared__ int s[512];
  const int tid = threadIdx.x;
  s[tid] = (tid < 343) ? cellcnt[tid] : 0;
  __syncthreads();
  for (int off = 1; off < 512; off <<= 1) {
    int v = (tid >= off) ? s[tid - off] : 0;
    __syncthreads();
    s[tid] += v;
    __syncthreads();
  }
  if (tid < 344) celloff[tid] = (tid == 0) ? 0 : s[tid - 1];
  cellcur[tid] = 0;
}

// K3: scatter atoms into cell-sorted storage (within-cell order arbitrary —
// downstream is order-independent by construction).
__global__ __launch_bounds__(256) void nl_scatter(const float* __restrict__ pos,
                                                  float* __restrict__ ws) {
  const int a = blockIdx.x * 256 + threadIdx.x;  // 8192 threads
  float x = pos[3 * a], y = pos[3 * a + 1], z = pos[3 * a + 2];
  int cl = cellco(x) + 7 * cellco(y) + 49 * cellco(z);
  int slot = ((const int*)(ws + W_CELLOFF))[cl] +
             atomicAdd(&((int*)(ws + W_CELLCUR))[cl], 1);
  ((float4*)(ws + W_SORTPOS))[slot] = make_float4(x, y, z, sq3_nc(x, y, z));
  ((unsigned short*)(ws + W_SORTID))[slot] = (unsigned short)a;
}

// K4: COUNT. One BLOCK per cell (343 x 512 = 8 waves). Stage the 27-cell
// neighborhood (concatenated x-strips) into LDS once; each wave counts one
// row per chunk against the LDS-resident list. Self always predicates true
// (d2_self ~ ±eps < cut, validated r5) -> cnt-1.
__global__ __launch_bounds__(512, 4) void nl_count(float* __restrict__ ws) {
  __shared__ float4 cp[CAPL];
  __shared__ int sg[9], scum[10];
  const int tid = threadIdx.x;
  const int lane = tid & 63;
  const int wave = tid >> 6;
  const int c = blockIdx.x;  // cell 0..342

  const int* __restrict__ celloff = (const int*)(ws + W_CELLOFF);
  const float4* __restrict__ sp4 = (const float4*)(ws + W_SORTPOS);
  const unsigned short* __restrict__ sid = (const unsigned short*)(ws + W_SORTID);
  int* rowcnt = (int*)(ws + W_ROWCNT);

  const int rs = celloff[c], re = celloff[c + 1];
  if (rs == re) return;  // uniform: no rows in this cell

  if (tid == 0) {  // strip metadata (cell-uniform), trivial serial work
    int ccx = c % 7, ccy = (c / 7) % 7, ccz = c / 49;
    int x0 = ccx > 0 ? ccx - 1 : 0, x1 = ccx < 6 ? ccx + 1 : 6;
    int y0 = ccy > 0 ? ccy - 1 : 0, y1 = ccy < 6 ? ccy + 1 : 6;
    int z0 = ccz > 0 ? ccz - 1 : 0, z1 = ccz < 6 ? ccz + 1 : 6;
    int ns = 0, cum = 0;
    for (int icz = z0; icz <= z1; ++icz)
      for (int icy = y0; icy <= y1; ++icy) {
        int cb = 7 * icy + 49 * icz;
        int st = celloff[cb + x0], en = celloff[cb + x1 + 1];
        sg[ns] = st; scum[ns] = cum; cum += en - st; ++ns;
      }
    for (; ns < 9; ++ns) { sg[ns] = 0; scum[ns] = cum; }  // pad zero-len strips
    scum[9] = cum;
  }
  __syncthreads();

  const int T = scum[9];
  for (int st = 0; st < 9; ++st) {  // stage (coalesced, ~2 sweeps total)
    int cs = scum[st], len = scum[st + 1] - cs;
    for (int i = tid; i < len; i += 512)
      if (cs + i < CAPL) cp[cs + i] = sp4[sg[st] + i];
  }
  __syncthreads();

  for (int sl = rs + wave; sl < re; sl += 8) {
    float4 pi = sp4[sl];  // exact bits of staged copy
    int cnt = 0;
    for (int bb = 0; bb < T; bb += 64) {
      int idx = bb + lane;
      bool v = idx < T;
      int i2 = v ? idx : T - 1;  // clamp; pred killed by v
      float4 p;
      if (i2 < CAPL) p = cp[i2];
      else {  // overflow fallback (dead for this input) — correct in principle
        int ss = 0;
        while (scum[ss + 1] <= i2) ++ss;
        p = sp4[sg[ss] + (i2 - scum[ss])];
      }
      float d2 = d2_gram(pi.x, pi.y, pi.z, pi.w, p.x, p.y, p.z, p.w);
      cnt += (v && d2 < D2_CUT) ? 1 : 0;
    }
    for (int off = 32; off > 0; off >>= 1) cnt += __shfl_down(cnt, off, 64);
    if (lane == 0) rowcnt[sid[sl]] = cnt - 1;  // remove self-pair
  }
}

// K5: exclusive scan of 8192 row counts.
__global__ __launch_bounds__(1024) void nl_rowscan(float* __restrict__ ws) {
  const int* cnts = (const int*)(ws + W_ROWCNT);
  int* offs = (int*)(ws + W_ROWOFF);
  __shared__ int s[1024];
  const int tid = threadIdx.x;
  const int base = tid * 8;
  int local[8];
  int sum = 0;
#pragma unroll
  for (int k = 0; k < 8; ++k) { local[k] = sum; sum += cnts[base + k]; }
  s[tid] = sum;
  __syncthreads();
  for (int off = 1; off < 1024; off <<= 1) {
    int v = (tid >= off) ? s[tid - off] : 0;
    __syncthreads();
    s[tid] += v;
    __syncthreads();
  }
  int excl = (tid == 0) ? 0 : s[tid - 1];
#pragma unroll
  for (int k = 0; k < 8; ++k) offs[base + k] = excl + local[k];
}

// K6: WRITE. Per-cell block, staged candidates (pos+id), r5-proven per-row
// bitmap -> word-ascending extraction (= reference j order) -> dense writes.
__global__ __launch_bounds__(512, 4) void nl_write(const float* __restrict__ pos,
                                                   float* __restrict__ out,
                                                   const float* __restrict__ ws) {
  __shared__ float4 cp[CAPL];              // 16 KB
  __shared__ unsigned short cid[CAPL];     // 2 KB
  __shared__ unsigned int bmap[8][256];    // 8 KB (8192 bits per wave)
  __shared__ unsigned short stj[8][CAP];   // 3 KB
  __shared__ int sg[9], scum[10];
  const int tid = threadIdx.x;
  const int lane = tid & 63;
  const int wave = tid >> 6;
  const int c = blockIdx.x;

  const int* __restrict__ celloff = (const int*)(ws + W_CELLOFF);
  const float4* __restrict__ sp4 = (const float4*)(ws + W_SORTPOS);
  const unsigned short* __restrict__ sid = (const unsigned short*)(ws + W_SORTID);
  const int* __restrict__ rowoff = (const int*)(ws + W_ROWOFF);

  const int rs = celloff[c], re = celloff[c + 1];
  if (rs == re) return;

  if (tid == 0) {
    int ccx = c % 7, ccy = (c / 7) % 7, ccz = c / 49;
    int x0 = ccx > 0 ? ccx - 1 : 0, x1 = ccx < 6 ? ccx + 1 : 6;
    int y0 = ccy > 0 ? ccy - 1 : 0, y1 = ccy < 6 ? ccy + 1 : 6;
    int z0 = ccz > 0 ? ccz - 1 : 0, z1 = ccz < 6 ? ccz + 1 : 6;
    int ns = 0, cum = 0;
    for (int icz = z0; icz <= z1; ++icz)
      for (int icy = y0; icy <= y1; ++icy) {
        int cb = 7 * icy + 49 * icz;
        int st = celloff[cb + x0], en = celloff[cb + x1 + 1];
        sg[ns] = st; scum[ns] = cum; cum += en - st; ++ns;
      }
    for (; ns < 9; ++ns) { sg[ns] = 0; scum[ns] = cum; }
    scum[9] = cum;
  }
  __syncthreads();

  const int T = scum[9];
  for (int st = 0; st < 9; ++st) {
    int cs = scum[st], len = scum[st + 1] - cs;
    for (int i = tid; i < len; i += 512)
      if (cs + i < CAPL) {
        cp[cs + i] = sp4[sg[st] + i];
        cid[cs + i] = sid[sg[st] + i];
      }
  }
  __syncthreads();

  for (int sl = rs + wave; sl < re; sl += 8) {
#pragma unroll
    for (int q = 0; q < 4; ++q) bmap[wave][lane + 64 * q] = 0u;  // wave-private
    float4 pi = sp4[sl];
    const int rid = sid[sl];

    for (int bb = 0; bb < T; bb += 64) {
      int idx = bb + lane;
      bool v = idx < T;
      int i2 = v ? idx : T - 1;
      float4 p; int jd;
      if (i2 < CAPL) { p = cp[i2]; jd = cid[i2]; }
      else {
        int ss = 0;
        while (scum[ss + 1] <= i2) ++ss;
        int gidx = sg[ss] + (i2 - scum[ss]);
        p = sp4[gidx]; jd = sid[gidx];
      }
      float d2 = d2_gram(pi.x, pi.y, pi.z, pi.w, p.x, p.y, p.z, p.w);
      if (v && d2 < D2_CUT)
        atomicOr(&bmap[wave][jd >> 5], 1u << (jd & 31));
    }
    if (lane == 0)  // self always marked; clear it
      atomicAnd(&bmap[wave][rid >> 5], ~(1u << (rid & 31)));

    // extract in ascending j: 4 segments of 64 words; popcount prefix (r5-proven)
    int ktot = 0;
#pragma unroll
    for (int seg = 0; seg < 4; ++seg) {
      int w = seg * 64 + lane;
      unsigned bits = bmap[wave][w];
      int pc = __popc(bits);
      int incl = pc;
      for (int d = 1; d < 64; d <<= 1) {
        int u = __shfl_up(incl, d, 64);
        if (lane >= d) incl += u;
      }
      int bpos = ktot + incl - pc;
      while (bits) {
        int b = __builtin_ctz(bits);
        bits &= bits - 1;
        if (bpos < CAP) stj[wave][bpos] = (unsigned short)(w * 32 + b);
        ++bpos;
      }
      ktot += __shfl(incl, 63, 64);
    }

    int k = ktot > CAP ? CAP : ktot;
    int ro = rowoff[rid];
    for (int s2 = lane; s2 < k; s2 += 64) {
      int j = stj[wave][s2];
      int o = ro + s2;
      if ((unsigned)o < MAXP) {
        float xj = pos[3 * j], yj = pos[3 * j + 1], zj = pos[3 * j + 2];
        float ds = sqrtf(d2_direct(pi.x, pi.y, pi.z, xj, yj, zj));
        ((float2*)out)[o] = make_float2((float)rid, (float)j);  // interleaved pair
        out[2 * MAXP + o] = (rid < j) ? 1.0f : 0.0f;            // buffer_scales
        out[3 * MAXP + o] = ds;                                 // ds
      }
    }
  }
}

extern "C" void kernel_launch(void* const* d_in, const int* in_sizes, int n_in,
                              void* d_out, int out_size, void* d_ws, size_t ws_size,
                              hipStream_t stream) {
  const float* pos = (const float*)d_in[0];  // float32 [8192,3]
  float* out = (float*)d_out;                // float32 [4*MAXP]
  float* ws = (float*)d_ws;

  nl_pack<<<256, 256, 0, stream>>>(out, ws);
  nl_cellcount<<<32, 256, 0, stream>>>(pos, ws);
  nl_cellscan<<<1, 512, 0, stream>>>(ws);
  nl_scatter<<<32, 256, 0, stream>>>(pos, ws);
  nl_count<<<343, 512, 0, stream>>>(ws);
  nl_rowscan<<<1, 1024, 0, stream>>>(ws);
  nl_write<<<343, 512, 0, stream>>>(pos, out, ws);
}

// Round 7
// 96.656 us; speedup vs baseline: 1.1595x; 1.1595x over previous
//
#include <hip/hip_runtime.h>

#define MAXP 1048576           // static pair bound (MAX_PAIRS)
#define NATOMS 8192
#define D2_CUT 0x1.8ffffep+4f  // fl(sqrt(s))<5  <=>  s < 25-2^-19
#define CINV 0.175f            // 7/40: 7^3=343 cells, width 5.714 > 5.0004 (conservative)
#define CAP 192                // max hits/row (avg ~67)

// d_ws layout (float offsets). Total 53760 floats = 210 KB (below r5-proven 214 KB).
#define W_SORTPOS 0            // float4[8192] cell-sorted (x,y,z,sq)
#define W_SORTID  32768        // u16[8192] sorted slot -> original atom id
#define W_ROWCNT  36864        // int[8192]
#define W_ROWOFF  45056        // int[8192]
#define W_CELLOFF 53248        // int[344], padded to 512

__device__ __forceinline__ float sq3_nc(float x, float y, float z) {
#pragma clang fp contract(off)
  float a = x * x;
  float b = y * y;
  float c = z * z;
  return (a + b) + c;
}

// mask per _pairwise_dist: sq_i + sq_j - 2*(x @ x.T); BLAS K=3 FMA chain (bit-exact, proven)
__device__ __forceinline__ float d2_gram(float xi, float yi, float zi, float sqi,
                                         float xj, float yj, float zj, float sqj) {
#pragma clang fp contract(off)
  float g = xi * xj;
  g = __builtin_fmaf(yi, yj, g);
  g = __builtin_fmaf(zi, zj, g);
  float t = sqi + sqj;
  float d2 = t - 2.0f * g;
  return d2;
}

__device__ __forceinline__ float d2_direct(float xi, float yi, float zi,
                                           float xj, float yj, float zj) {
#pragma clang fp contract(off)
  float dx = xj - xi;
  float dy = yj - yi;
  float dz = zj - zi;
  float a = dx * dx;
  float b = dy * dy;
  float c = dz * dz;
  return (a + b) + c;
}

__device__ __forceinline__ int cellco(float v) {
  int c = (int)(v * CINV);
  return c < 0 ? 0 : (c > 6 ? 6 : c);
}

// K0: zero 16.8 MB output (padding must be exactly 0). Full-chip grid.
__global__ __launch_bounds__(256) void nl_pack(float* __restrict__ out) {
  const int gtid = blockIdx.x * 256 + threadIdx.x;  // 65536 threads
  float4* o4 = (float4*)out;                        // 4*MAXP floats = 1,048,576 float4
#pragma unroll
  for (int k = 0; k < 16; ++k)
    o4[k * 65536 + gtid] = make_float4(0.f, 0.f, 0.f, 0.f);
}

// K1: single block: bin + scan + scatter entirely in LDS (r0-proven structure;
// sortid stored as u16 per r5). One launch replaces cellcount+cellscan+scatter.
__global__ __launch_bounds__(1024) void nl_prep(const float* __restrict__ pos,
                                                float* __restrict__ ws) {
  __shared__ int hcnt[343];
  __shared__ int hoff[344];
  __shared__ int hcur[343];
  __shared__ int s[512];
  const int tid = threadIdx.x;
  if (tid < 343) { hcnt[tid] = 0; hcur[tid] = 0; }
  __syncthreads();

  float x[8], y[8], z[8];
  int cl[8];
#pragma unroll
  for (int k = 0; k < 8; ++k) {
    int a = tid + k * 1024;
    x[k] = pos[3 * a]; y[k] = pos[3 * a + 1]; z[k] = pos[3 * a + 2];
    cl[k] = cellco(x[k]) + 7 * cellco(y[k]) + 49 * cellco(z[k]);
    atomicAdd(&hcnt[cl[k]], 1);
  }
  __syncthreads();

  if (tid < 512) s[tid] = (tid < 343) ? hcnt[tid] : 0;
  __syncthreads();
  for (int off = 1; off < 512; off <<= 1) {
    int v = (tid < 512 && tid >= off) ? s[tid - off] : 0;
    __syncthreads();
    if (tid < 512) s[tid] += v;
    __syncthreads();
  }
  if (tid < 343) hoff[tid] = (tid == 0) ? 0 : s[tid - 1];
  if (tid == 343) hoff[343] = NATOMS;
  __syncthreads();
  if (tid < 344) ((int*)(ws + W_CELLOFF))[tid] = hoff[tid];

  unsigned short* sortid = (unsigned short*)(ws + W_SORTID);
  float4* sortpos = (float4*)(ws + W_SORTPOS);
#pragma unroll
  for (int k = 0; k < 8; ++k) {
    int slot = hoff[cl[k]] + atomicAdd(&hcur[cl[k]], 1);
    sortid[slot] = (unsigned short)(tid + k * 1024);
    sortpos[slot] = make_float4(x[k], y[k], z[k], sq3_nc(x[k], y[k], z[k]));
  }
}

// K2: COUNT. One wave per SORTED slot (adjacent waves share cells -> L1 hits),
// 8192 waves all co-resident at 8/SIMD. Per-lane predicate accumulate, one
// shuffle-reduce. Self always predicates true (d2_self ~ ±eps < cut, proven
// r5/r6) -> cnt-1. GRID 2048 x 256.
__global__ __launch_bounds__(256, 8) void nl_count(float* __restrict__ ws) {
  const int lane = threadIdx.x & 63;
  const int wave = threadIdx.x >> 6;
  const int slot = blockIdx.x * 4 + wave;  // sorted slot 0..8191

  const float4* __restrict__ sp4 = (const float4*)(ws + W_SORTPOS);
  const unsigned short* __restrict__ sid = (const unsigned short*)(ws + W_SORTID);
  const int* __restrict__ celloff = (const int*)(ws + W_CELLOFF);
  int* rowcnt = (int*)(ws + W_ROWCNT);

  const float4 pi = sp4[slot];  // bit-identical to pos-derived (x,y,z,sq)
  int cx = cellco(pi.x), cy = cellco(pi.y), cz = cellco(pi.z);
  int x0 = max(cx - 1, 0), x1 = min(cx + 1, 6);
  int y0 = max(cy - 1, 0), y1 = min(cy + 1, 6);
  int z0 = max(cz - 1, 0), z1 = min(cz + 1, 6);

  int cnt = 0;
  for (int icz = z0; icz <= z1; ++icz)
    for (int icy = y0; icy <= y1; ++icy) {
      int cb = 7 * icy + 49 * icz;
      int st = celloff[cb + x0];
      int en = celloff[cb + x1 + 1];
      for (int bb = st; bb < en; bb += 64) {
        int t = bb + lane;
        bool v = t < en;
        int t2 = v ? t : (en - 1);  // clamp: valid slot; pred killed by v
        float4 p = sp4[t2];
        float d2 = d2_gram(pi.x, pi.y, pi.z, pi.w, p.x, p.y, p.z, p.w);
        cnt += (v && d2 < D2_CUT) ? 1 : 0;
      }
    }
  for (int off = 32; off > 0; off >>= 1) cnt += __shfl_down(cnt, off, 64);
  if (lane == 0) rowcnt[sid[slot]] = cnt - 1;  // remove self-pair
}

// K3: exclusive scan of 8192 row counts.
__global__ __launch_bounds__(1024) void nl_rowscan(float* __restrict__ ws) {
  const int* cnts = (const int*)(ws + W_ROWCNT);
  int* offs = (int*)(ws + W_ROWOFF);
  __shared__ int s[1024];
  const int tid = threadIdx.x;
  const int base = tid * 8;
  int local[8];
  int sum = 0;
#pragma unroll
  for (int k = 0; k < 8; ++k) { local[k] = sum; sum += cnts[base + k]; }
  s[tid] = sum;
  __syncthreads();
  for (int off = 1; off < 1024; off <<= 1) {
    int v = (tid >= off) ? s[tid - off] : 0;
    __syncthreads();
    s[tid] += v;
    __syncthreads();
  }
  int excl = (tid == 0) ? 0 : s[tid - 1];
#pragma unroll
  for (int k = 0; k < 8; ++k) offs[base + k] = excl + local[k];
}

// K4: WRITE. One wave per SORTED slot; r5-proven per-row bitmap (mark by
// ORIGINAL j, order-independent) -> word-ascending extraction (= reference j
// order) -> dense writes with bit-exact d2_direct+sqrtf on raw pos.
// GRID 2048 x 256, 8 waves/SIMD.
__global__ __launch_bounds__(256, 8) void nl_write(const float* __restrict__ pos,
                                                   float* __restrict__ out,
                                                   const float* __restrict__ ws) {
  __shared__ unsigned int bmap[4][256];    // 8192 bits per wave (wave-private)
  __shared__ unsigned short stj[4][CAP];   // ascending j-list per wave
  const int lane = threadIdx.x & 63;
  const int wave = threadIdx.x >> 6;
  const int slot = blockIdx.x * 4 + wave;  // sorted slot 0..8191

  const float4* __restrict__ sp4 = (const float4*)(ws + W_SORTPOS);
  const unsigned short* __restrict__ sid = (const unsigned short*)(ws + W_SORTID);
  const int* __restrict__ celloff = (const int*)(ws + W_CELLOFF);
  const int* __restrict__ rowoff = (const int*)(ws + W_ROWOFF);

#pragma unroll
  for (int q = 0; q < 4; ++q) bmap[wave][lane + 64 * q] = 0u;

  const float4 pi = sp4[slot];
  const int rid = sid[slot];
  int cx = cellco(pi.x), cy = cellco(pi.y), cz = cellco(pi.z);
  int x0 = max(cx - 1, 0), x1 = min(cx + 1, 6);
  int y0 = max(cy - 1, 0), y1 = min(cy + 1, 6);
  int z0 = max(cz - 1, 0), z1 = min(cz + 1, 6);

  for (int icz = z0; icz <= z1; ++icz)
    for (int icy = y0; icy <= y1; ++icy) {
      int cb = 7 * icy + 49 * icz;
      int st = celloff[cb + x0];
      int en = celloff[cb + x1 + 1];
      for (int bb = st; bb < en; bb += 64) {
        int t = bb + lane;
        bool v = t < en;
        int t2 = v ? t : (en - 1);  // identical clamp as nl_count
        float4 p = sp4[t2];
        int jd = sid[t2];
        float d2 = d2_gram(pi.x, pi.y, pi.z, pi.w, p.x, p.y, p.z, p.w);
        if (v && d2 < D2_CUT)
          atomicOr(&bmap[wave][jd >> 5], 1u << (jd & 31));
      }
    }
  if (lane == 0)  // self always marked; clear it
    atomicAnd(&bmap[wave][rid >> 5], ~(1u << (rid & 31)));

  // extract in ascending j: 4 segments of 64 words; popcount prefix (proven)
  int ktot = 0;
#pragma unroll
  for (int seg = 0; seg < 4; ++seg) {
    int w = seg * 64 + lane;
    unsigned bits = bmap[wave][w];
    int pc = __popc(bits);
    int incl = pc;
    for (int d = 1; d < 64; d <<= 1) {
      int u = __shfl_up(incl, d, 64);
      if (lane >= d) incl += u;
    }
    int bpos = ktot + incl - pc;
    while (bits) {
      int b = __builtin_ctz(bits);
      bits &= bits - 1;
      if (bpos < CAP) stj[wave][bpos] = (unsigned short)(w * 32 + b);
      ++bpos;
    }
    ktot += __shfl(incl, 63, 64);
  }

  int k = ktot > CAP ? CAP : ktot;
  int ro = rowoff[rid];
  for (int s2 = lane; s2 < k; s2 += 64) {
    int j = stj[wave][s2];
    int o = ro + s2;
    if ((unsigned)o < MAXP) {
      float xj = pos[3 * j], yj = pos[3 * j + 1], zj = pos[3 * j + 2];
      float ds = sqrtf(d2_direct(pi.x, pi.y, pi.z, xj, yj, zj));
      ((float2*)out)[o] = make_float2((float)rid, (float)j);  // interleaved pair
      out[2 * MAXP + o] = (rid < j) ? 1.0f : 0.0f;            // buffer_scales
      out[3 * MAXP + o] = ds;                                 // ds
    }
  }
}

extern "C" void kernel_launch(void* const* d_in, const int* in_sizes, int n_in,
                              void* d_out, int out_size, void* d_ws, size_t ws_size,
                              hipStream_t stream) {
  const float* pos = (const float*)d_in[0];  // float32 [8192,3]
  float* out = (float*)d_out;                // float32 [4*MAXP]
  float* ws = (float*)d_ws;

  nl_pack<<<256, 256, 0, stream>>>(out);
  nl_prep<<<1, 1024, 0, stream>>>(pos, ws);
  nl_count<<<2048, 256, 0, stream>>>(ws);
  nl_rowscan<<<1, 1024, 0, stream>>>(ws);
  nl_write<<<2048, 256, 0, stream>>>(pos, out, ws);
}